// Round 11
// baseline (1942.865 us; speedup 1.0000x reference)
//
#include <hip/hip_runtime.h>

// ============================================================================
// RetinaNetHead (S2ANet-style rotated head), MI355X gfx950.
// R11: B operand DIRECT FROM GLOBAL to registers (saddr loads, per-lane
//      voffsets). R10 cycle-accounting showed MFMA(1242c) + LDS(1536c) fully
//      serialized per phase-slot (2900c measured ~= their sum): LDS was a
//      second saturated pipe. B is L1/L2-resident weights -> move its traffic
//      to the (idle) L1/L2 path; LDS keeps only A (dbuf 16KB, R8 swizzle).
//      + T5 setprio(1) around MFMA cluster (2 blocks/CU -> role diversity).
// Per phase (BK=32): stage A(ph+1) via gload_lds; load 8 B frags to regs;
// 4 ds_read A; 32 MFMA; __syncthreads (A drain has full MFMA window).
// fp32 accum; logits/decode fp32.
//
// Level geometry: rows gm 0..174591; cum={0,131072,163840,172032,174080,174592}
// Workspace (ushort units), same footprint (~245.1MB):
//   [0) feats NHWC fp16 (reused as t2) | [44,695,552) t1r | [78,249,984) t1c
//   [111,804,416) conv w 4x[9][256][256] | [114,163,712) wh | [114,171,904) wc
//   [114,188,288) zp | byte 228,376,704: hbuf fp32 [174592][24]
// ============================================================================

typedef __attribute__((ext_vector_type(8))) _Float16 f16x8;
typedef __attribute__((ext_vector_type(4))) float f32x4;

#define SCORES_TOTAL 10475520ull  // 8*87296*15

__device__ __forceinline__ unsigned short f2h(float f) {
  union { _Float16 h; unsigned short u; } x;
  x.h = (_Float16)f;
  return x.u;
}

__device__ __forceinline__ float sigmf(float x) {
  return 1.0f / (1.0f + expf(-x));
}

__device__ __forceinline__ void gload_lds16(const unsigned short* g,
                                            unsigned short* l) {
  __builtin_amdgcn_global_load_lds(
      (const __attribute__((address_space(1))) unsigned int*)g,
      (__attribute__((address_space(3))) unsigned int*)l, 16, 0, 0);
}

__device__ __forceinline__ void lvl_lookup(int gm, int& logW, int& mbase) {
  if (gm < 131072) { logW = 7; mbase = 0; }
  else if (gm < 163840) { logW = 6; mbase = 131072; }
  else if (gm < 172032) { logW = 5; mbase = 163840; }
  else if (gm < 174080) { logW = 4; mbase = 172032; }
  else { logW = 3; mbase = 174080; }
}

// ---------------------------------------------------------------- weight prep
__global__ __launch_bounds__(256) void prep_convw(
    const float* __restrict__ w0, const float* __restrict__ w1,
    const float* __restrict__ w2, const float* __restrict__ w3,
    unsigned short* __restrict__ wtout) {
  int g = blockIdx.x * 256 + threadIdx.x;  // < 4*589824
  int q = g >> 16;
  int wsel = q / 9;
  int kk = q - wsel * 9;
  int r = g & 65535;
  int oc = r >> 8, ic = r & 255;
  const float* src = (wsel == 0) ? w0 : (wsel == 1) ? w1 : (wsel == 2) ? w2 : w3;
  float v = src[(size_t)(oc * 256 + ic) * 9 + kk];
  wtout[(size_t)wsel * 589824 + (size_t)((kk << 8) + oc) * 256 + ic] = f2h(v);
}

__global__ __launch_bounds__(256) void prep_small(
    const float* __restrict__ clsh, const float* __restrict__ regh,
    const float* __restrict__ confw,
    unsigned short* __restrict__ wc, unsigned short* __restrict__ wh,
    unsigned short* __restrict__ zp) {
  int g = blockIdx.x * 256 + threadIdx.x;
  if (g < 16384) {
    int row = g >> 8, ic = g & 255;
    float v = (row < 60) ? clsh[row * 256 + ic] : 0.0f;
    wc[g] = f2h(v);
  } else if (g < 24576) {
    int gg = g - 16384;
    int row = gg >> 8, ic = gg & 255;
    float v = 0.0f;
    if (row < 20) v = regh[row * 256 + ic];
    else if (row < 24) v = confw[(row - 20) * 256 + ic];
    wh[gg] = f2h(v);
  } else if (g < 24640) {
    zp[g - 24576] = 0;
  }
}

// ------------------------------- NCHW fp32 -> NHWC fp16, all levels merged
__global__ __launch_bounds__(256) void to_nhwc_all(
    const float* __restrict__ f0, const float* __restrict__ f1,
    const float* __restrict__ f2, const float* __restrict__ f3,
    const float* __restrict__ f4, unsigned short* __restrict__ out) {
  __shared__ unsigned short L[64][258];
  const int t = threadIdx.x;
  const int gm0 = blockIdx.x * 64;
  int logW, mbase;
  const float* in;
  if (gm0 < 131072) { logW = 7; mbase = 0; in = f0; }
  else if (gm0 < 163840) { logW = 6; mbase = 131072; in = f1; }
  else if (gm0 < 172032) { logW = 5; mbase = 163840; in = f2; }
  else if (gm0 < 174080) { logW = 4; mbase = 172032; in = f3; }
  else { logW = 3; mbase = 174080; in = f4; }
  const int logHW = 2 * logW;
  const int HW = 1 << logHW;
  const int lm0 = gm0 - mbase;
  const int b = lm0 >> logHW;
  const int hw0 = lm0 & (HW - 1);
#pragma unroll
  for (int it = 0; it < 16; ++it) {
    int c = it * 16 + (t >> 4);
    int j4 = (t & 15) * 4;
    float4 v = *reinterpret_cast<const float4*>(
        in + (size_t)(b * 256 + c) * HW + hw0 + j4);
    L[j4 + 0][c] = f2h(v.x);
    L[j4 + 1][c] = f2h(v.y);
    L[j4 + 2][c] = f2h(v.z);
    L[j4 + 3][c] = f2h(v.w);
  }
  __syncthreads();
#pragma unroll
  for (int it = 0; it < 16; ++it) {
    int j = it * 4 + (t >> 6);
    int c4 = (t & 63) * 4;
    unsigned v0 = (unsigned)L[j][c4 + 0] | ((unsigned)L[j][c4 + 1] << 16);
    unsigned v1 = (unsigned)L[j][c4 + 2] | ((unsigned)L[j][c4 + 3] << 16);
    uint2 v = make_uint2(v0, v1);
    *reinterpret_cast<uint2*>(out + ((size_t)(gm0 + j) << 8) + c4) = v;
  }
}

// ------- conv1 both towers fused: 128Mx128N, BK32, A-LDS dbuf + B-from-L2
__global__ __launch_bounds__(256, 2) void conv1f(
    const unsigned short* __restrict__ xin,   // absolute rows [gm][256]
    const unsigned short* __restrict__ wtR,
    const unsigned short* __restrict__ wtC,
    const float* __restrict__ biasR, const float* __restrict__ biasC,
    const unsigned short* __restrict__ zp,
    unsigned short* __restrict__ outR,        // group-local rows
    unsigned short* __restrict__ outC, int gm_base) {
  __shared__ unsigned short pool[16384];  // A dbuf 2x4096 elems; epilogue 32KB
  const int t = threadIdx.x;
  const int lane = t & 63;
  const int wv = t >> 6;
  const int wm = wv >> 1, wn = wv & 1;
  const int gm0 = gm_base + blockIdx.x * 128;
  const int n0 = blockIdx.y << 7;
  int logW, mbase;
  lvl_lookup(gm0, logW, mbase);
  const int logHW = 2 * logW;
  const int H = 1 << logW, W = H;
  const int HWm1 = (1 << logHW) - 1, Wm1 = W - 1;

  // A staging (R8 pattern, swizzled source chunk; rule #21 involution)
  const int srow = lane >> 2;                               // 0..15
  const int schk = (((lane & 3) ^ ((lane >> 3) & 3)) << 3);
  int hjj[2], wjj[2];
  const unsigned short* aptrj[2];
  const int sldrow = (wv << 5);
#pragma unroll
  for (int j = 0; j < 2; ++j) {
    int gm = gm0 + sldrow + (j << 4) + srow;
    int lm = gm - mbase;
    int hw = lm & HWm1;
    hjj[j] = hw >> logW;
    wjj[j] = hw & Wm1;
    aptrj[j] = xin + ((size_t)gm << 8) + schk;
  }

  // B voffsets (per-lane constant); scalar base advances per phase
  const int brow = (wn << 6) + (lane & 15);
  const int kgrp = (lane >> 4) << 3;
  const unsigned short* wtRn = wtR + ((size_t)n0 << 8);
  const unsigned short* wtCn = wtC + ((size_t)n0 << 8);
  int voff[4];
#pragma unroll
  for (int nf = 0; nf < 4; ++nf)
    voff[nf] = ((brow + (nf << 4)) << 8) + kgrp;

  f32x4 accR[4][4], accC[4][4];
#pragma unroll
  for (int i = 0; i < 4; ++i)
#pragma unroll
    for (int j = 0; j < 4; ++j) {
      accR[i][j] = (f32x4){0.f, 0.f, 0.f, 0.f};
      accC[i][j] = (f32x4){0.f, 0.f, 0.f, 0.f};
    }

  const int arow = (wm << 6) + (lane & 15);
  const int sxor = ((lane & 15) >> 1) & 3;
  const int achk = ((lane >> 4) ^ sxor) << 3;

  auto STAGEA = [&](int p, int buf) {
    int icp = p / 9;
    int kk = p - icp * 9;
    int k3 = kk / 3;
    int dy = k3 - 1, dxv = kk - k3 * 3 - 1;
    int moff = ((dy << logW) + dxv) << 8;
    int ic0 = icp << 5;
    const int ab = buf << 12;
#pragma unroll
    for (int j = 0; j < 2; ++j) {
      bool valid = ((unsigned)(hjj[j] + dy) < (unsigned)H) &
                   ((unsigned)(wjj[j] + dxv) < (unsigned)W);
      const unsigned short* g = valid ? (aptrj[j] + moff + ic0) : zp;
      gload_lds16(g, pool + ab + ((sldrow + (j << 4)) << 5));
    }
  };

  STAGEA(0, 0);
  __syncthreads();

  int cur = 0;
#pragma unroll 1
  for (int ph = 0; ph < 72; ++ph) {
    if (ph < 71) STAGEA(ph + 1, cur ^ 1);
    // B frags for THIS phase, straight from L1/L2
    f16x8 bR[4], bC[4];
    {
      int icp = ph / 9;
      int kk = ph - icp * 9;
      int bko = (kk << 16) + (icp << 5);
      const unsigned short* pR = wtRn + bko;
      const unsigned short* pC = wtCn + bko;
#pragma unroll
      for (int nf = 0; nf < 4; ++nf) {
        bR[nf] = *reinterpret_cast<const f16x8*>(pR + voff[nf]);
        bC[nf] = *reinterpret_cast<const f16x8*>(pC + voff[nf]);
      }
    }
    const int cb = cur << 12;
    f16x8 a[4];
#pragma unroll
    for (int mf = 0; mf < 4; ++mf)
      a[mf] = *reinterpret_cast<const f16x8*>(
          pool + cb + ((arow + (mf << 4)) << 5) + achk);
    __builtin_amdgcn_s_setprio(1);
#pragma unroll
    for (int mf = 0; mf < 4; ++mf)
#pragma unroll
      for (int nf = 0; nf < 4; ++nf) {
        accR[mf][nf] = __builtin_amdgcn_mfma_f32_16x16x32_f16(
            a[mf], bR[nf], accR[mf][nf], 0, 0, 0);
        accC[mf][nf] = __builtin_amdgcn_mfma_f32_16x16x32_f16(
            a[mf], bC[nf], accC[mf][nf], 0, 0, 0);
      }
    __builtin_amdgcn_s_setprio(0);
    __syncthreads();
    cur ^= 1;
  }

  // ---- vectorized epilogue: acc -> LDS f16 -> 16B stores
  const int erow = t >> 1;
  const int ech = t & 1;
  const unsigned short* esrc =
      pool + ((((erow >> 6) << 1) + ech) << 12) + ((erow & 63) << 6);
  unsigned short* ep = pool + (wv << 12);
  const int eg = (lane >> 4) << 2;
  const int el = lane & 15;
  const int lrow0 = gm0 - gm_base;

#pragma unroll
  for (int nf = 0; nf < 4; ++nf) {
    float bi = biasR[n0 + (wn << 6) + (nf << 4) + el];
#pragma unroll
    for (int mf = 0; mf < 4; ++mf)
#pragma unroll
      for (int r = 0; r < 4; ++r)
        ep[((mf << 4) + eg + r) * 64 + (nf << 4) + el] =
            f2h(fmaxf(accR[mf][nf][r] + bi, 0.0f));
  }
  __syncthreads();
  {
    unsigned short* edst =
        outR + ((size_t)(lrow0 + erow) << 8) + n0 + (ech << 6);
#pragma unroll
    for (int q = 0; q < 8; ++q)
      reinterpret_cast<uint4*>(edst)[q] =
          reinterpret_cast<const uint4*>(esrc)[q];
  }
  __syncthreads();
#pragma unroll
  for (int nf = 0; nf < 4; ++nf) {
    float bi = biasC[n0 + (wn << 6) + (nf << 4) + el];
#pragma unroll
    for (int mf = 0; mf < 4; ++mf)
#pragma unroll
      for (int r = 0; r < 4; ++r)
        ep[((mf << 4) + eg + r) * 64 + (nf << 4) + el] =
            f2h(fmaxf(accC[mf][nf][r] + bi, 0.0f));
  }
  __syncthreads();
  {
    unsigned short* edst =
        outC + ((size_t)(lrow0 + erow) << 8) + n0 + (ech << 6);
#pragma unroll
    for (int q = 0; q < 8; ++q)
      reinterpret_cast<uint4*>(edst)[q] =
          reinterpret_cast<const uint4*>(esrc)[q];
  }
}

// ------------- conv2: 128Mx256N, BK32, A-LDS dbuf + B-from-L2
__global__ __launch_bounds__(256, 2) void conv2w(
    const unsigned short* __restrict__ xin,  // group-local rows
    const unsigned short* __restrict__ wt,
    const float* __restrict__ bias,
    const unsigned short* __restrict__ zp,
    unsigned short* __restrict__ yout,       // absolute rows
    int gm_base) {
  __shared__ unsigned short pool[16384];     // A dbuf 2x4096; epilogue 32KB
  const int t = threadIdx.x;
  const int lane = t & 63;
  const int wv = t >> 6;
  const int wm = wv >> 1, wn = wv & 1;       // wave tile 64M x 128N
  const int gm0 = gm_base + blockIdx.x * 128;
  int logW, mbase;
  lvl_lookup(gm0, logW, mbase);
  const int logHW = 2 * logW;
  const int H = 1 << logW, W = H;
  const int HWm1 = (1 << logHW) - 1, Wm1 = W - 1;

  const int srow = lane >> 2;
  const int schk = (((lane & 3) ^ ((lane >> 3) & 3)) << 3);
  int hjj[2], wjj[2];
  const unsigned short* aptrj[2];
  const int sldrow = (wv << 5);
#pragma unroll
  for (int j = 0; j < 2; ++j) {
    int gm = gm0 + sldrow + (j << 4) + srow;
    int lm = gm - mbase;
    int hw = lm & HWm1;
    hjj[j] = hw >> logW;
    wjj[j] = hw & Wm1;
    aptrj[j] = xin + ((size_t)(gm - gm_base) << 8) + schk;
  }

  const int brow = (wn << 7) + (lane & 15);
  const int kgrp = (lane >> 4) << 3;
  int voff[8];
#pragma unroll
  for (int nf = 0; nf < 8; ++nf)
    voff[nf] = ((brow + (nf << 4)) << 8) + kgrp;

  f32x4 acc[4][8];
#pragma unroll
  for (int i = 0; i < 4; ++i)
#pragma unroll
    for (int j = 0; j < 8; ++j) acc[i][j] = (f32x4){0.f, 0.f, 0.f, 0.f};

  const int arow = (wm << 6) + (lane & 15);
  const int sxor = ((lane & 15) >> 1) & 3;
  const int achk = ((lane >> 4) ^ sxor) << 3;

  auto STAGEA = [&](int p, int buf) {
    int icp = p / 9;
    int kk = p - icp * 9;
    int k3 = kk / 3;
    int dy = k3 - 1, dxv = kk - k3 * 3 - 1;
    int moff = ((dy << logW) + dxv) << 8;
    int ic0 = icp << 5;
    const int ab = buf << 12;
#pragma unroll
    for (int j = 0; j < 2; ++j) {
      bool valid = ((unsigned)(hjj[j] + dy) < (unsigned)H) &
                   ((unsigned)(wjj[j] + dxv) < (unsigned)W);
      const unsigned short* g = valid ? (aptrj[j] + moff + ic0) : zp;
      gload_lds16(g, pool + ab + ((sldrow + (j << 4)) << 5));
    }
  };

  STAGEA(0, 0);
  __syncthreads();

  int cur = 0;
#pragma unroll 1
  for (int ph = 0; ph < 72; ++ph) {
    if (ph < 71) STAGEA(ph + 1, cur ^ 1);
    f16x8 b[8];
    {
      int icp = ph / 9;
      int kk = ph - icp * 9;
      int bko = (kk << 16) + (icp << 5);
      const unsigned short* pB = wt + bko;
#pragma unroll
      for (int nf = 0; nf < 8; ++nf)
        b[nf] = *reinterpret_cast<const f16x8*>(pB + voff[nf]);
    }
    const int cb = cur << 12;
    f16x8 a[4];
#pragma unroll
    for (int mf = 0; mf < 4; ++mf)
      a[mf] = *reinterpret_cast<const f16x8*>(
          pool + cb + ((arow + (mf << 4)) << 5) + achk);
    __builtin_amdgcn_s_setprio(1);
#pragma unroll
    for (int mf = 0; mf < 4; ++mf)
#pragma unroll
      for (int nf = 0; nf < 8; ++nf)
        acc[mf][nf] = __builtin_amdgcn_mfma_f32_16x16x32_f16(
            a[mf], b[nf], acc[mf][nf], 0, 0, 0);
    __builtin_amdgcn_s_setprio(0);
    __syncthreads();
    cur ^= 1;
  }

  // ---- vectorized epilogue, two 64-col halves
  const int erow = t >> 1;
  const int ech = t & 1;
  const unsigned short* esrc =
      pool + ((((erow >> 6) << 1) + ech) << 12) + ((erow & 63) << 6);
  unsigned short* ep = pool + (wv << 12);
  const int eg = (lane >> 4) << 2;
  const int el = lane & 15;

#pragma unroll
  for (int h = 0; h < 2; ++h) {
    __syncthreads();
#pragma unroll
    for (int q4 = 0; q4 < 4; ++q4) {
      int nf = (h << 2) + q4;
      float bi = bias[(wn << 7) + (nf << 4) + el];
#pragma unroll
      for (int mf = 0; mf < 4; ++mf)
#pragma unroll
        for (int r = 0; r < 4; ++r)
          ep[((mf << 4) + eg + r) * 64 + (q4 << 4) + el] =
              f2h(fmaxf(acc[mf][nf][r] + bi, 0.0f));
    }
    __syncthreads();
    unsigned short* edst =
        yout + ((size_t)(gm0 + erow) << 8) + (ech << 7) + (h << 6);
#pragma unroll
    for (int q = 0; q < 8; ++q)
      reinterpret_cast<uint4*>(edst)[q] =
          reinterpret_cast<const uint4*>(esrc)[q];
  }
}

// -------------------------------------------- bbox(20)+conf(4) head -> hbuf
__global__ __launch_bounds__(256) void head24_mfma(
    const unsigned short* __restrict__ t2,  // group-local rows
    const unsigned short* __restrict__ wh,
    const float* __restrict__ regb, const float* __restrict__ confb,
    float* __restrict__ hbuf) {             // group-local rows
  const int t = threadIdx.x, lane = t & 63, wv = t >> 6;
  const int rowb = blockIdx.x * 256 + wv * 64;
  const int kgrp = (lane >> 4) << 3;
  const int l15 = lane & 15;
  f32x4 acc[4][2];
#pragma unroll
  for (int i = 0; i < 4; ++i)
#pragma unroll
    for (int j = 0; j < 2; ++j) acc[i][j] = (f32x4){0.f, 0.f, 0.f, 0.f};
#pragma unroll
  for (int k0 = 0; k0 < 256; k0 += 32) {
    f16x8 a[4], b[2];
#pragma unroll
    for (int mf = 0; mf < 4; ++mf)
      a[mf] = *reinterpret_cast<const f16x8*>(
          t2 + (((size_t)(rowb + (mf << 4) + l15)) << 8) + k0 + kgrp);
#pragma unroll
    for (int nf = 0; nf < 2; ++nf)
      b[nf] = *reinterpret_cast<const f16x8*>(
          wh + (size_t)(((nf << 4) + l15) << 8) + k0 + kgrp);
#pragma unroll
    for (int mf = 0; mf < 4; ++mf)
#pragma unroll
      for (int nf = 0; nf < 2; ++nf)
        acc[mf][nf] = __builtin_amdgcn_mfma_f32_16x16x32_f16(
            a[mf], b[nf], acc[mf][nf], 0, 0, 0);
  }
#pragma unroll
  for (int nf = 0; nf < 2; ++nf) {
    int c = (nf << 4) + l15;
    if (c < 24) {
      float bi = (c < 20) ? regb[c] : confb[c - 20];
#pragma unroll
      for (int mf = 0; mf < 4; ++mf)
#pragma unroll
        for (int r = 0; r < 4; ++r) {
          int m = rowb + (mf << 4) + ((lane >> 4) << 2) + r;
          hbuf[(size_t)m * 24 + c] = acc[mf][nf][r] + bi;
        }
    }
  }
}

// ------------------------------------------- cls head + sigmoid*sigmoid out
__global__ __launch_bounds__(256) void cls_scores(
    const unsigned short* __restrict__ t2,  // absolute rows (ws base)
    const unsigned short* __restrict__ wcw,
    const float* __restrict__ clsb,
    const float* __restrict__ hbuf,         // absolute rows
    float* __restrict__ outs, int gm_base) {
  const int t = threadIdx.x, lane = t & 63, wv = t >> 6;
  const int gm0 = gm_base + blockIdx.x * 256;
  int logW, mbase, lvl_off;
  if (gm0 < 131072) { logW = 7; mbase = 0; lvl_off = 0; }
  else if (gm0 < 163840) { logW = 6; mbase = 131072; lvl_off = 65536; }
  else if (gm0 < 172032) { logW = 5; mbase = 163840; lvl_off = 81920; }
  else if (gm0 < 174080) { logW = 4; mbase = 172032; lvl_off = 86016; }
  else { logW = 3; mbase = 174080; lvl_off = 87040; }
  const int logHW = 2 * logW, HWm1 = (1 << logHW) - 1;
  const int rowb = gm0 + wv * 64;
  const int kgrp = (lane >> 4) << 3;
  const int l15 = lane & 15;
  f32x4 acc[4][4];
#pragma unroll
  for (int i = 0; i < 4; ++i)
#pragma unroll
    for (int j = 0; j < 4; ++j) acc[i][j] = (f32x4){0.f, 0.f, 0.f, 0.f};
#pragma unroll
  for (int k0 = 0; k0 < 256; k0 += 32) {
    f16x8 a[4], b[4];
#pragma unroll
    for (int mf = 0; mf < 4; ++mf)
      a[mf] = *reinterpret_cast<const f16x8*>(
          t2 + (((size_t)(rowb + (mf << 4) + l15)) << 8) + k0 + kgrp);
#pragma unroll
    for (int nf = 0; nf < 4; ++nf)
      b[nf] = *reinterpret_cast<const f16x8*>(
          wcw + (size_t)(((nf << 4) + l15) << 8) + k0 + kgrp);
#pragma unroll
    for (int mf = 0; mf < 4; ++mf)
#pragma unroll
      for (int nf = 0; nf < 4; ++nf)
        acc[mf][nf] = __builtin_amdgcn_mfma_f32_16x16x32_f16(
            a[mf], b[nf], acc[mf][nf], 0, 0, 0);
  }
#pragma unroll
  for (int nf = 0; nf < 4; ++nf) {
    int c = (nf << 4) + l15;
    if (c < 60) {
      int ai = c / 15, ci = c - ai * 15;
      float bi = clsb[c];
#pragma unroll
      for (int mf = 0; mf < 4; ++mf)
#pragma unroll
        for (int r = 0; r < 4; ++r) {
          int m = rowb + (mf << 4) + ((lane >> 4) << 2) + r;
          float logit = acc[mf][nf][r] + bi;
          float conf = hbuf[(size_t)m * 24 + 20 + ai];
          float sc = sigmf(logit) * sigmf(conf);
          int lm = m - mbase;
          int b = lm >> logHW;
          int hw = lm & HWm1;
          int loc = lvl_off + (hw << 2) + ai;
          outs[(size_t)b * 1309440 + (size_t)loc * 15 + ci] = sc;
        }
    }
  }
}

// ------------------------------------------------- rbox decode, all levels
__global__ __launch_bounds__(256) void decode_all(
    const float* __restrict__ hbuf, float* __restrict__ outb) {
  int tid = blockIdx.x * 256 + threadIdx.x;
  if (tid >= 174592 * 4) return;
  int m = tid >> 2, a = tid & 3;
  int logW, mbase, lvl_off;
  float stride;
  if (m < 131072) { logW = 7; mbase = 0; lvl_off = 0; stride = 8.f; }
  else if (m < 163840) { logW = 6; mbase = 131072; lvl_off = 65536; stride = 16.f; }
  else if (m < 172032) { logW = 5; mbase = 163840; lvl_off = 81920; stride = 32.f; }
  else if (m < 174080) { logW = 4; mbase = 172032; lvl_off = 86016; stride = 64.f; }
  else { logW = 3; mbase = 174080; lvl_off = 87040; stride = 128.f; }
  const int logHW = 2 * logW;
  const float ANG[4] = {-0.39269908169872414f, 0.39269908169872414f,
                        1.1780972450961724f, 1.9634954084936207f};
  const float* d = hbuf + (size_t)m * 24 + a * 5;
  float dx = d[0], dy = d[1], dw = d[2], dh = d[3], da = d[4];
  int lm = m - mbase;
  int b = lm >> logHW, hw = lm & ((1 << logHW) - 1);
  int h = hw >> logW, w = hw & ((1 << logW) - 1);
  float ctr = 0.5f * (stride - 1.0f);
  float rx = w * stride + ctr, ry = h * stride + ctr;
  float rw = stride * 1.6329931618554521f;  // 4/sqrt(6)
  float rh = stride * 9.7979589711327124f;  // 4*sqrt(6)
  const float MR = 13.815510557964274f;     // |log(1e-6)|
  dw = fminf(fmaxf(dw, -MR), MR);
  dh = fminf(fmaxf(dh, -MR), MR);
  float gx = dx * rw + rx;
  float gy = dy * rh + ry;
  float gw = rw * expf(dw);
  float gh = rh * expf(dh);
  float v = da + ANG[a] + 0.7853981633974483f;
  float r = fmodf(v, 3.14159265358979323846f);
  if (r < 0.0f) r += 3.14159265358979323846f;
  float ga = r - 0.7853981633974483f;
  int loc = lvl_off + (hw << 2) + a;
  size_t base = (size_t)b * 436480 + (size_t)loc * 5;
  outb[base + 0] = gx;
  outb[base + 1] = gy;
  outb[base + 2] = gw;
  outb[base + 3] = gh;
  outb[base + 4] = ga;
}

// ============================================================================
extern "C" void kernel_launch(void* const* d_in, const int* in_sizes, int n_in,
                              void* d_out, int out_size, void* d_ws,
                              size_t ws_size, hipStream_t stream) {
  const float* feats[5];
  for (int i = 0; i < 5; ++i) feats[i] = (const float*)d_in[i];
  const float* reg_w0 = (const float*)d_in[5];
  const float* reg_b0 = (const float*)d_in[6];
  const float* reg_w1 = (const float*)d_in[7];
  const float* reg_b1 = (const float*)d_in[8];
  const float* cls_w0 = (const float*)d_in[9];
  const float* cls_b0 = (const float*)d_in[10];
  const float* cls_w1 = (const float*)d_in[11];
  const float* cls_b1 = (const float*)d_in[12];
  const float* reg_head_w = (const float*)d_in[13];
  const float* reg_head_b = (const float*)d_in[14];
  const float* cls_head_w = (const float*)d_in[15];
  const float* cls_head_b = (const float*)d_in[16];
  const float* conf_w = (const float*)d_in[17];
  const float* conf_b = (const float*)d_in[18];

  unsigned short* ws = (unsigned short*)d_ws;
  unsigned short* t1r = ws + 44695552ull;
  unsigned short* t1c = ws + 78249984ull;
  unsigned short* wt4 = ws + 111804416ull;
  unsigned short* wh = ws + 114163712ull;
  unsigned short* wc = ws + 114171904ull;
  unsigned short* zp = ws + 114188288ull;
  float* hbuf_all = (float*)((char*)d_ws + 228376704ull);

  prep_convw<<<9216, 256, 0, stream>>>(reg_w0, reg_w1, cls_w0, cls_w1, wt4);
  prep_small<<<97, 256, 0, stream>>>(cls_head_w, reg_head_w, conf_w, wc, wh,
                                     zp);
  to_nhwc_all<<<2728, 256, 0, stream>>>(feats[0], feats[1], feats[2], feats[3],
                                        feats[4], ws);

  float* scores = (float*)d_out;
  float* boxes = (float*)d_out + SCORES_TOTAL;

  static const int gbase[2] = {0, 131072};
  static const int gM[2] = {131072, 43520};
  for (int g = 0; g < 2; ++g) {
    const int base = gbase[g];
    const int M = gM[g];
    conv1f<<<dim3(M / 128, 2), 256, 0, stream>>>(
        ws, wt4 + 0ull * 589824, wt4 + 2ull * 589824, reg_b0, cls_b0, zp, t1r,
        t1c, base);
    conv2w<<<M / 128, 256, 0, stream>>>(t1r, wt4 + 1ull * 589824, reg_b1, zp,
                                        ws, base);
    head24_mfma<<<M / 256, 256, 0, stream>>>(
        ws + ((size_t)base << 8), wh, reg_head_b, conf_b,
        hbuf_all + (size_t)base * 24);
    conv2w<<<M / 128, 256, 0, stream>>>(t1c, wt4 + 3ull * 589824, cls_b1, zp,
                                        ws, base);
    cls_scores<<<M / 256, 256, 0, stream>>>(ws, wc, cls_head_b, hbuf_all,
                                            scores, base);
  }
  decode_all<<<(174592 * 4 + 255) / 256, 256, 0, stream>>>(hbuf_all, boxes);
}

// Round 12
// 1079.889 us; speedup vs baseline: 1.7991x; 1.7991x over previous
//
#include <hip/hip_runtime.h>

// ============================================================================
// RetinaNetHead (S2ANet-style rotated head), MI355X gfx950.
// R12: conv rebuilt on the 256^2 8-phase template (guide §5, m201): R8-R10 all
//      plateaued at ~868 TF = the m97 2-barrier ceiling; R11's B-from-global
//      regressed 2x (L1 path slower than LDS). This is the documented escape:
//      512thr/8 waves, 256x256 tile, BK=64, A+B dbuf LDS 128KB, 4 phases per
//      K-step each {ds_read frags || stage || bar || lgkm0 || 16 MFMA || bar},
//      vmcnt(0) once per K-step (stages get 2.5+ phases of flight), XOR chunk
//      swizzle both-sides (rule #21), setprio around MFMA (T5).
// fp32 accum; logits/decode fp32. Non-conv kernels unchanged from R10.
//
// Level geometry: rows gm 0..174591; cum={0,131072,163840,172032,174080,174592}
// Workspace (ushort units), same footprint (~245.1MB):
//   [0) feats NHWC fp16 (reused as t2) | [44,695,552) t1r | [78,249,984) t1c
//   [111,804,416) conv w 4x[9][256][256] | [114,163,712) wh | [114,171,904) wc
//   [114,188,288) zp | byte 228,376,704: hbuf fp32 [174592][24]
// ============================================================================

typedef __attribute__((ext_vector_type(8))) _Float16 f16x8;
typedef __attribute__((ext_vector_type(4))) float f32x4;

#define SCORES_TOTAL 10475520ull  // 8*87296*15

__device__ __forceinline__ unsigned short f2h(float f) {
  union { _Float16 h; unsigned short u; } x;
  x.h = (_Float16)f;
  return x.u;
}

__device__ __forceinline__ float sigmf(float x) {
  return 1.0f / (1.0f + expf(-x));
}

__device__ __forceinline__ void gload_lds16(const unsigned short* g,
                                            unsigned short* l) {
  __builtin_amdgcn_global_load_lds(
      (const __attribute__((address_space(1))) unsigned int*)g,
      (__attribute__((address_space(3))) unsigned int*)l, 16, 0, 0);
}

__device__ __forceinline__ void lvl_lookup(int gm, int& logW, int& mbase) {
  if (gm < 131072) { logW = 7; mbase = 0; }
  else if (gm < 163840) { logW = 6; mbase = 131072; }
  else if (gm < 172032) { logW = 5; mbase = 163840; }
  else if (gm < 174080) { logW = 4; mbase = 172032; }
  else { logW = 3; mbase = 174080; }
}

// ---------------------------------------------------------------- weight prep
__global__ __launch_bounds__(256) void prep_convw(
    const float* __restrict__ w0, const float* __restrict__ w1,
    const float* __restrict__ w2, const float* __restrict__ w3,
    unsigned short* __restrict__ wtout) {
  int g = blockIdx.x * 256 + threadIdx.x;  // < 4*589824
  int q = g >> 16;
  int wsel = q / 9;
  int kk = q - wsel * 9;
  int r = g & 65535;
  int oc = r >> 8, ic = r & 255;
  const float* src = (wsel == 0) ? w0 : (wsel == 1) ? w1 : (wsel == 2) ? w2 : w3;
  float v = src[(size_t)(oc * 256 + ic) * 9 + kk];
  wtout[(size_t)wsel * 589824 + (size_t)((kk << 8) + oc) * 256 + ic] = f2h(v);
}

__global__ __launch_bounds__(256) void prep_small(
    const float* __restrict__ clsh, const float* __restrict__ regh,
    const float* __restrict__ confw,
    unsigned short* __restrict__ wc, unsigned short* __restrict__ wh,
    unsigned short* __restrict__ zp) {
  int g = blockIdx.x * 256 + threadIdx.x;
  if (g < 16384) {
    int row = g >> 8, ic = g & 255;
    float v = (row < 60) ? clsh[row * 256 + ic] : 0.0f;
    wc[g] = f2h(v);
  } else if (g < 24576) {
    int gg = g - 16384;
    int row = gg >> 8, ic = gg & 255;
    float v = 0.0f;
    if (row < 20) v = regh[row * 256 + ic];
    else if (row < 24) v = confw[(row - 20) * 256 + ic];
    wh[gg] = f2h(v);
  } else if (g < 24640) {
    zp[g - 24576] = 0;
  }
}

// ------------------------------- NCHW fp32 -> NHWC fp16, all levels merged
__global__ __launch_bounds__(256) void to_nhwc_all(
    const float* __restrict__ f0, const float* __restrict__ f1,
    const float* __restrict__ f2, const float* __restrict__ f3,
    const float* __restrict__ f4, unsigned short* __restrict__ out) {
  __shared__ unsigned short L[64][258];
  const int t = threadIdx.x;
  const int gm0 = blockIdx.x * 64;
  int logW, mbase;
  const float* in;
  if (gm0 < 131072) { logW = 7; mbase = 0; in = f0; }
  else if (gm0 < 163840) { logW = 6; mbase = 131072; in = f1; }
  else if (gm0 < 172032) { logW = 5; mbase = 163840; in = f2; }
  else if (gm0 < 174080) { logW = 4; mbase = 172032; in = f3; }
  else { logW = 3; mbase = 174080; in = f4; }
  const int logHW = 2 * logW;
  const int HW = 1 << logHW;
  const int lm0 = gm0 - mbase;
  const int b = lm0 >> logHW;
  const int hw0 = lm0 & (HW - 1);
#pragma unroll
  for (int it = 0; it < 16; ++it) {
    int c = it * 16 + (t >> 4);
    int j4 = (t & 15) * 4;
    float4 v = *reinterpret_cast<const float4*>(
        in + (size_t)(b * 256 + c) * HW + hw0 + j4);
    L[j4 + 0][c] = f2h(v.x);
    L[j4 + 1][c] = f2h(v.y);
    L[j4 + 2][c] = f2h(v.z);
    L[j4 + 3][c] = f2h(v.w);
  }
  __syncthreads();
#pragma unroll
  for (int it = 0; it < 16; ++it) {
    int j = it * 4 + (t >> 6);
    int c4 = (t & 63) * 4;
    unsigned v0 = (unsigned)L[j][c4 + 0] | ((unsigned)L[j][c4 + 1] << 16);
    unsigned v1 = (unsigned)L[j][c4 + 2] | ((unsigned)L[j][c4 + 3] << 16);
    uint2 v = make_uint2(v0, v1);
    *reinterpret_cast<uint2*>(out + ((size_t)(gm0 + j) << 8) + c4) = v;
  }
}

// ------------------- conv3x3: 256Mx256N tile, BK=64, 4-phase/K-step schedule
__global__ __launch_bounds__(512, 2) void conv256(
    const unsigned short* __restrict__ xin,   // virtual base: rows at abs gm
    const unsigned short* __restrict__ wt,    // [9][256 oc][256 ic] fp16
    const float* __restrict__ bias,
    const unsigned short* __restrict__ zp,
    unsigned short* __restrict__ yout,        // virtual base: rows at abs gm
    int gm_base) {
  __shared__ unsigned short pool[65536];      // A 2x32KB | B 2x32KB (128KB)
  const int t = threadIdx.x;
  const int lane = t & 63;
  const int wv = t >> 6;       // 0..7
  const int wm = wv >> 2;      // 0..1  -> rows wm*128..+127
  const int wn = wv & 3;       // 0..3  -> cols wn*64..+63
  const int gm0 = gm_base + blockIdx.x * 256;
  int logW, mbase;
  lvl_lookup(gm0, logW, mbase);
  const int logHW = 2 * logW;
  const int H = 1 << logW, W = H;
  const int HWm1 = (1 << logHW) - 1, Wm1 = W - 1;

  // ---- staging precompute (4 A-slots + 4 B-slots per thread, 16B each)
  // chunk swizzle (rule #21, both sides): chunk ^= row&7; here lane-constant.
  const int schk = ((lane & 7) ^ ((lane >> 3) & 7)) << 3;  // elem offset
  int hj[4], wj[4];
  const unsigned short* aptr[4];
  const unsigned short* bptr[4];
#pragma unroll
  for (int i = 0; i < 4; ++i) {
    int r = (wv << 5) + (i << 3) + (lane >> 3);  // 0..255 (row / oc)
    int gm = gm0 + r;
    int lm = gm - mbase;
    int hw = lm & HWm1;
    hj[i] = hw >> logW;
    wj[i] = hw & Wm1;
    aptr[i] = xin + ((size_t)gm << 8) + schk;
    bptr[i] = wt + ((size_t)r << 8) + schk;
  }

  f32x4 acc[8][4];
#pragma unroll
  for (int i = 0; i < 8; ++i)
#pragma unroll
    for (int j = 0; j < 4; ++j) acc[i][j] = (f32x4){0.f, 0.f, 0.f, 0.f};

  const int l15 = lane & 15;
  const int arow0 = (wm << 7) + l15;  // A row base (within 256)
  const int brow0 = (wn << 6) + l15;  // B row base (oc)
  int achkb[2];
#pragma unroll
  for (int ks = 0; ks < 2; ++ks)
    achkb[ks] = ((((ks << 2) + (lane >> 4)) ^ (lane & 7)) << 4);  // bytes

  // phase p of 36: icq = p/9 (ic0 = icq*64), kk = p%9 (tap)
  auto STAGE_A = [&](int p, int bsel) {
    int icq = p / 9;
    int kk = p - icq * 9;
    int k3 = kk / 3;
    int dy = k3 - 1, dxv = kk - k3 * 3 - 1;
    int moff = ((dy << logW) + dxv) << 8;
    int ico = icq << 6;
    unsigned short* dst = pool + (bsel << 14) + (wv << 11);
#pragma unroll
    for (int i = 0; i < 4; ++i) {
      bool valid = ((unsigned)(hj[i] + dy) < (unsigned)H) &
                   ((unsigned)(wj[i] + dxv) < (unsigned)W);
      const unsigned short* g = valid ? (aptr[i] + moff + ico) : zp;
      gload_lds16(g, dst + (i << 9));
    }
  };
  auto STAGE_B = [&](int p, int bsel) {
    int icq = p / 9;
    int kk = p - icq * 9;
    int boff = (kk << 16) + (icq << 6);
    unsigned short* dst = pool + 32768 + (bsel << 14) + (wv << 11);
#pragma unroll
    for (int i = 0; i < 4; ++i)
      gload_lds16(bptr[i] + boff, dst + (i << 9));
  };

  // ---- prologue: stage K-step 0 fully into buffer 0
  STAGE_A(0, 0);
  STAGE_B(0, 0);
  asm volatile("s_waitcnt vmcnt(0)" ::: "memory");
  __builtin_amdgcn_s_barrier();

#pragma unroll 1
  for (int tt = 0; tt < 36; ++tt) {
    const int c = tt & 1, nb = c ^ 1;
    const char* Ab = (const char*)pool + (c << 15);
    const char* Bb = (const char*)pool + 65536 + (c << 15);
    f16x8 a[4], b0[4], b1[4];

    // ---------- phase 0: ks0, mf 0..3, read b0; stage A(t+1)
#pragma unroll
    for (int mf = 0; mf < 4; ++mf)
      a[mf] = *reinterpret_cast<const f16x8*>(
          Ab + ((arow0 + (mf << 4)) << 7) + achkb[0]);
#pragma unroll
    for (int nf = 0; nf < 4; ++nf)
      b0[nf] = *reinterpret_cast<const f16x8*>(
          Bb + ((brow0 + (nf << 4)) << 7) + achkb[0]);
    if (tt < 35) STAGE_A(tt + 1, nb);
    __builtin_amdgcn_s_barrier();
    asm volatile("s_waitcnt lgkmcnt(0)" ::: "memory");
    __builtin_amdgcn_sched_barrier(0);
    __builtin_amdgcn_s_setprio(1);
#pragma unroll
    for (int mf = 0; mf < 4; ++mf)
#pragma unroll
      for (int nf = 0; nf < 4; ++nf)
        acc[mf][nf] = __builtin_amdgcn_mfma_f32_16x16x32_f16(
            a[mf], b0[nf], acc[mf][nf], 0, 0, 0);
    __builtin_amdgcn_s_setprio(0);
    __builtin_amdgcn_s_barrier();

    // ---------- phase 1: ks0, mf 4..7; stage B(t+1)
#pragma unroll
    for (int mf = 0; mf < 4; ++mf)
      a[mf] = *reinterpret_cast<const f16x8*>(
          Ab + ((arow0 + ((mf + 4) << 4)) << 7) + achkb[0]);
    if (tt < 35) STAGE_B(tt + 1, nb);
    __builtin_amdgcn_s_barrier();
    asm volatile("s_waitcnt lgkmcnt(0)" ::: "memory");
    __builtin_amdgcn_sched_barrier(0);
    __builtin_amdgcn_s_setprio(1);
#pragma unroll
    for (int mf = 0; mf < 4; ++mf)
#pragma unroll
      for (int nf = 0; nf < 4; ++nf)
        acc[mf + 4][nf] = __builtin_amdgcn_mfma_f32_16x16x32_f16(
            a[mf], b0[nf], acc[mf + 4][nf], 0, 0, 0);
    __builtin_amdgcn_s_setprio(0);
    __builtin_amdgcn_s_barrier();

    // ---------- phase 2: ks1, mf 0..3, read b1
#pragma unroll
    for (int mf = 0; mf < 4; ++mf)
      a[mf] = *reinterpret_cast<const f16x8*>(
          Ab + ((arow0 + (mf << 4)) << 7) + achkb[1]);
#pragma unroll
    for (int nf = 0; nf < 4; ++nf)
      b1[nf] = *reinterpret_cast<const f16x8*>(
          Bb + ((brow0 + (nf << 4)) << 7) + achkb[1]);
    __builtin_amdgcn_s_barrier();
    asm volatile("s_waitcnt lgkmcnt(0)" ::: "memory");
    __builtin_amdgcn_sched_barrier(0);
    __builtin_amdgcn_s_setprio(1);
#pragma unroll
    for (int mf = 0; mf < 4; ++mf)
#pragma unroll
      for (int nf = 0; nf < 4; ++nf)
        acc[mf][nf] = __builtin_amdgcn_mfma_f32_16x16x32_f16(
            a[mf], b1[nf], acc[mf][nf], 0, 0, 0);
    __builtin_amdgcn_s_setprio(0);
    __builtin_amdgcn_s_barrier();

    // ---------- phase 3: ks1, mf 4..7; drain stages before buffer swap
#pragma unroll
    for (int mf = 0; mf < 4; ++mf)
      a[mf] = *reinterpret_cast<const f16x8*>(
          Ab + ((arow0 + ((mf + 4) << 4)) << 7) + achkb[1]);
    asm volatile("s_waitcnt vmcnt(0)" ::: "memory");  // stages(t+1) complete
    __builtin_amdgcn_s_barrier();
    asm volatile("s_waitcnt lgkmcnt(0)" ::: "memory");
    __builtin_amdgcn_sched_barrier(0);
    __builtin_amdgcn_s_setprio(1);
#pragma unroll
    for (int mf = 0; mf < 4; ++mf)
#pragma unroll
      for (int nf = 0; nf < 4; ++nf)
        acc[mf + 4][nf] = __builtin_amdgcn_mfma_f32_16x16x32_f16(
            a[mf], b1[nf], acc[mf + 4][nf], 0, 0, 0);
    __builtin_amdgcn_s_setprio(0);
    __builtin_amdgcn_s_barrier();
  }
  __syncthreads();  // all LDS reads retired before epilogue overwrites pool

  // ---- epilogue: acc -> pool[256][256] fp16 (bias+relu) -> 256B/thread out
  {
    const int eg = (lane >> 4) << 2;
    const int el = lane & 15;
#pragma unroll
    for (int nf = 0; nf < 4; ++nf) {
      float bi = bias[(wn << 6) + (nf << 4) + el];
#pragma unroll
      for (int mf = 0; mf < 8; ++mf)
#pragma unroll
        for (int r = 0; r < 4; ++r) {
          int wrow = (wm << 7) + (mf << 4) + eg + r;
          pool[(wrow << 8) + (wn << 6) + (nf << 4) + el] =
              f2h(fmaxf(acc[mf][nf][r] + bi, 0.0f));
        }
    }
  }
  __syncthreads();
  {
    const int row = t >> 1;
    const int half = t & 1;
    const unsigned short* src = pool + (row << 8) + (half << 7);
    unsigned short* dst = yout + ((size_t)(gm0 + row) << 8) + (half << 7);
#pragma unroll
    for (int q = 0; q < 16; ++q)
      reinterpret_cast<uint4*>(dst)[q] =
          reinterpret_cast<const uint4*>(src)[q];
  }
}

// -------------------------------------------- bbox(20)+conf(4) head -> hbuf
__global__ __launch_bounds__(256) void head24_mfma(
    const unsigned short* __restrict__ t2,  // group-local rows
    const unsigned short* __restrict__ wh,
    const float* __restrict__ regb, const float* __restrict__ confb,
    float* __restrict__ hbuf) {             // group-local rows
  const int t = threadIdx.x, lane = t & 63, wv = t >> 6;
  const int rowb = blockIdx.x * 256 + wv * 64;
  const int kgrp = (lane >> 4) << 3;
  const int l15 = lane & 15;
  f32x4 acc[4][2];
#pragma unroll
  for (int i = 0; i < 4; ++i)
#pragma unroll
    for (int j = 0; j < 2; ++j) acc[i][j] = (f32x4){0.f, 0.f, 0.f, 0.f};
#pragma unroll
  for (int k0 = 0; k0 < 256; k0 += 32) {
    f16x8 a[4], b[2];
#pragma unroll
    for (int mf = 0; mf < 4; ++mf)
      a[mf] = *reinterpret_cast<const f16x8*>(
          t2 + (((size_t)(rowb + (mf << 4) + l15)) << 8) + k0 + kgrp);
#pragma unroll
    for (int nf = 0; nf < 2; ++nf)
      b[nf] = *reinterpret_cast<const f16x8*>(
          wh + (size_t)(((nf << 4) + l15) << 8) + k0 + kgrp);
#pragma unroll
    for (int mf = 0; mf < 4; ++mf)
#pragma unroll
      for (int nf = 0; nf < 2; ++nf)
        acc[mf][nf] = __builtin_amdgcn_mfma_f32_16x16x32_f16(
            a[mf], b[nf], acc[mf][nf], 0, 0, 0);
  }
#pragma unroll
  for (int nf = 0; nf < 2; ++nf) {
    int c = (nf << 4) + l15;
    if (c < 24) {
      float bi = (c < 20) ? regb[c] : confb[c - 20];
#pragma unroll
      for (int mf = 0; mf < 4; ++mf)
#pragma unroll
        for (int r = 0; r < 4; ++r) {
          int m = rowb + (mf << 4) + ((lane >> 4) << 2) + r;
          hbuf[(size_t)m * 24 + c] = acc[mf][nf][r] + bi;
        }
    }
  }
}

// ------------------------------------------- cls head + sigmoid*sigmoid out
__global__ __launch_bounds__(256) void cls_scores(
    const unsigned short* __restrict__ t2,  // absolute rows (ws base)
    const unsigned short* __restrict__ wcw,
    const float* __restrict__ clsb,
    const float* __restrict__ hbuf,         // absolute rows
    float* __restrict__ outs, int gm_base) {
  const int t = threadIdx.x, lane = t & 63, wv = t >> 6;
  const int gm0 = gm_base + blockIdx.x * 256;
  int logW, mbase, lvl_off;
  if (gm0 < 131072) { logW = 7; mbase = 0; lvl_off = 0; }
  else if (gm0 < 163840) { logW = 6; mbase = 131072; lvl_off = 65536; }
  else if (gm0 < 172032) { logW = 5; mbase = 163840; lvl_off = 81920; }
  else if (gm0 < 174080) { logW = 4; mbase = 172032; lvl_off = 86016; }
  else { logW = 3; mbase = 174080; lvl_off = 87040; }
  const int logHW = 2 * logW, HWm1 = (1 << logHW) - 1;
  const int rowb = gm0 + wv * 64;
  const int kgrp = (lane >> 4) << 3;
  const int l15 = lane & 15;
  f32x4 acc[4][4];
#pragma unroll
  for (int i = 0; i < 4; ++i)
#pragma unroll
    for (int j = 0; j < 4; ++j) acc[i][j] = (f32x4){0.f, 0.f, 0.f, 0.f};
#pragma unroll
  for (int k0 = 0; k0 < 256; k0 += 32) {
    f16x8 a[4], b[4];
#pragma unroll
    for (int mf = 0; mf < 4; ++mf)
      a[mf] = *reinterpret_cast<const f16x8*>(
          t2 + (((size_t)(rowb + (mf << 4) + l15)) << 8) + k0 + kgrp);
#pragma unroll
    for (int nf = 0; nf < 4; ++nf)
      b[nf] = *reinterpret_cast<const f16x8*>(
          wcw + (size_t)(((nf << 4) + l15) << 8) + k0 + kgrp);
#pragma unroll
    for (int mf = 0; mf < 4; ++mf)
#pragma unroll
      for (int nf = 0; nf < 4; ++nf)
        acc[mf][nf] = __builtin_amdgcn_mfma_f32_16x16x32_f16(
            a[mf], b[nf], acc[mf][nf], 0, 0, 0);
  }
#pragma unroll
  for (int nf = 0; nf < 4; ++nf) {
    int c = (nf << 4) + l15;
    if (c < 60) {
      int ai = c / 15, ci = c - ai * 15;
      float bi = clsb[c];
#pragma unroll
      for (int mf = 0; mf < 4; ++mf)
#pragma unroll
        for (int r = 0; r < 4; ++r) {
          int m = rowb + (mf << 4) + ((lane >> 4) << 2) + r;
          float logit = acc[mf][nf][r] + bi;
          float conf = hbuf[(size_t)m * 24 + 20 + ai];
          float sc = sigmf(logit) * sigmf(conf);
          int lm = m - mbase;
          int b = lm >> logHW;
          int hw = lm & HWm1;
          int loc = lvl_off + (hw << 2) + ai;
          outs[(size_t)b * 1309440 + (size_t)loc * 15 + ci] = sc;
        }
    }
  }
}

// ------------------------------------------------- rbox decode, all levels
__global__ __launch_bounds__(256) void decode_all(
    const float* __restrict__ hbuf, float* __restrict__ outb) {
  int tid = blockIdx.x * 256 + threadIdx.x;
  if (tid >= 174592 * 4) return;
  int m = tid >> 2, a = tid & 3;
  int logW, mbase, lvl_off;
  float stride;
  if (m < 131072) { logW = 7; mbase = 0; lvl_off = 0; stride = 8.f; }
  else if (m < 163840) { logW = 6; mbase = 131072; lvl_off = 65536; stride = 16.f; }
  else if (m < 172032) { logW = 5; mbase = 163840; lvl_off = 81920; stride = 32.f; }
  else if (m < 174080) { logW = 4; mbase = 172032; lvl_off = 86016; stride = 64.f; }
  else { logW = 3; mbase = 174080; lvl_off = 87040; stride = 128.f; }
  const int logHW = 2 * logW;
  const float ANG[4] = {-0.39269908169872414f, 0.39269908169872414f,
                        1.1780972450961724f, 1.9634954084936207f};
  const float* d = hbuf + (size_t)m * 24 + a * 5;
  float dx = d[0], dy = d[1], dw = d[2], dh = d[3], da = d[4];
  int lm = m - mbase;
  int b = lm >> logHW, hw = lm & ((1 << logHW) - 1);
  int h = hw >> logW, w = hw & ((1 << logW) - 1);
  float ctr = 0.5f * (stride - 1.0f);
  float rx = w * stride + ctr, ry = h * stride + ctr;
  float rw = stride * 1.6329931618554521f;  // 4/sqrt(6)
  float rh = stride * 9.7979589711327124f;  // 4*sqrt(6)
  const float MR = 13.815510557964274f;     // |log(1e-6)|
  dw = fminf(fmaxf(dw, -MR), MR);
  dh = fminf(fmaxf(dh, -MR), MR);
  float gx = dx * rw + rx;
  float gy = dy * rh + ry;
  float gw = rw * expf(dw);
  float gh = rh * expf(dh);
  float v = da + ANG[a] + 0.7853981633974483f;
  float r = fmodf(v, 3.14159265358979323846f);
  if (r < 0.0f) r += 3.14159265358979323846f;
  float ga = r - 0.7853981633974483f;
  int loc = lvl_off + (hw << 2) + a;
  size_t base = (size_t)b * 436480 + (size_t)loc * 5;
  outb[base + 0] = gx;
  outb[base + 1] = gy;
  outb[base + 2] = gw;
  outb[base + 3] = gh;
  outb[base + 4] = ga;
}

// ============================================================================
extern "C" void kernel_launch(void* const* d_in, const int* in_sizes, int n_in,
                              void* d_out, int out_size, void* d_ws,
                              size_t ws_size, hipStream_t stream) {
  const float* feats[5];
  for (int i = 0; i < 5; ++i) feats[i] = (const float*)d_in[i];
  const float* reg_w0 = (const float*)d_in[5];
  const float* reg_b0 = (const float*)d_in[6];
  const float* reg_w1 = (const float*)d_in[7];
  const float* reg_b1 = (const float*)d_in[8];
  const float* cls_w0 = (const float*)d_in[9];
  const float* cls_b0 = (const float*)d_in[10];
  const float* cls_w1 = (const float*)d_in[11];
  const float* cls_b1 = (const float*)d_in[12];
  const float* reg_head_w = (const float*)d_in[13];
  const float* reg_head_b = (const float*)d_in[14];
  const float* cls_head_w = (const float*)d_in[15];
  const float* cls_head_b = (const float*)d_in[16];
  const float* conf_w = (const float*)d_in[17];
  const float* conf_b = (const float*)d_in[18];

  unsigned short* ws = (unsigned short*)d_ws;
  unsigned short* t1r = ws + 44695552ull;
  unsigned short* t1c = ws + 78249984ull;
  unsigned short* wt4 = ws + 111804416ull;
  unsigned short* wh = ws + 114163712ull;
  unsigned short* wc = ws + 114171904ull;
  unsigned short* zp = ws + 114188288ull;
  float* hbuf_all = (float*)((char*)d_ws + 228376704ull);

  prep_convw<<<9216, 256, 0, stream>>>(reg_w0, reg_w1, cls_w0, cls_w1, wt4);
  prep_small<<<97, 256, 0, stream>>>(cls_head_w, reg_head_w, conf_w, wc, wh,
                                     zp);
  to_nhwc_all<<<2728, 256, 0, stream>>>(feats[0], feats[1], feats[2], feats[3],
                                        feats[4], ws);

  float* scores = (float*)d_out;
  float* boxes = (float*)d_out + SCORES_TOTAL;

  static const int gbase[2] = {0, 131072};
  static const int gM[2] = {131072, 43520};
  for (int g = 0; g < 2; ++g) {
    const int base = gbase[g];
    const int M = gM[g];
    const size_t bofs = ((size_t)base << 8);
    unsigned short* t1r_v = t1r - bofs;  // group-local virtual bases
    unsigned short* t1c_v = t1c - bofs;
    conv256<<<M / 256, 512, 0, stream>>>(ws, wt4 + 0ull * 589824, reg_b0, zp,
                                         t1r_v, base);
    conv256<<<M / 256, 512, 0, stream>>>(ws, wt4 + 2ull * 589824, cls_b0, zp,
                                         t1c_v, base);
    conv256<<<M / 256, 512, 0, stream>>>(t1r_v, wt4 + 1ull * 589824, reg_b1,
                                         zp, ws, base);
    head24_mfma<<<M / 256, 256, 0, stream>>>(
        ws + bofs, wh, reg_head_b, conf_b, hbuf_all + (size_t)base * 24);
    conv256<<<M / 256, 512, 0, stream>>>(t1c_v, wt4 + 3ull * 589824, cls_b1,
                                         zp, ws, base);
    cls_scores<<<M / 256, 256, 0, stream>>>(ws, wc, cls_head_b, hbuf_all,
                                            scores, base);
  }
  decode_all<<<(174592 * 4 + 255) / 256, 256, 0, stream>>>(hbuf_all, boxes);
}